// Round 2
// baseline (187.644 us; speedup 1.0000x reference)
//
#include <hip/hip_runtime.h>

// TreeCRF belief propagation, B=2048, C=2, L=2048, BRANCH=4.
// One block per batch element; per-b BP state lives entirely in LDS (32 KB).
// Static tree: parent(i) = (i-1)>>2; children of p are 4p+1..4p+4 (node 511
// has only 3 children: 2045..2047). Level starts {0,1,5,21,85,341,1365}.
//
// Upward pass is CHILD-per-lane (stride-1 LDS addresses, conflict-free) with
// a 4-lane shfl_xor reduce into the parent. Downward pass is node-per-lane
// (parent reads are 4-lane broadcasts, free). The 2x2047 live pairs entries
// are compacted once per launch into d_ws (child-indexed -> coalesced loads,
// L2-resident at 65 KB).

constexpr int NLAB = 2048;
constexpr int NBATCH = 2048;

__device__ __forceinline__ float lse2(float a, float b) {
    float m = fmaxf(a, b);
    return m + log1pf(__expf(-fabsf(a - b)));
}

__global__ __launch_bounds__(256) void compact_pairs(
    const float4* __restrict__ pairs4,  // (L, L) of float4 {yA=0yB=0, 01, 10, 11}
    float4* __restrict__ up,            // up[i]   = pairs[parent(i+1)][i+1]
    float4* __restrict__ down)          // down[i] = pairs[i+1][parent(i+1)]
{
    int i = blockIdx.x * 256 + threadIdx.x;
    if (i < NLAB - 1) {
        int c = i + 1, p = i >> 2;
        up[i]   = pairs4[(size_t)p * NLAB + c];
        down[i] = pairs4[(size_t)c * NLAB + p];
    }
}

template <bool COMPACT>
__global__ __launch_bounds__(256) void treecrf_kernel(
    const float* __restrict__ em_g,     // (B, 2, L)
    const float4* __restrict__ pairs4,  // fallback path
    const float4* __restrict__ up,
    const float4* __restrict__ down,
    float* __restrict__ out)            // (B, 2, L)
{
    // em: interleaved [l*2+c]; during the downward pass it is overwritten in
    // place with pb[l][c] = emissions[l][c] + beta[l][c] (children only need
    // em[par]+beta[par], and the final score = alpha + pb).
    __shared__ float em[2 * NLAB];
    __shared__ float al[2 * NLAB];   // alpha accumulator, interleaved [l*2+c]

    const int b = blockIdx.x;
    const int tid = threadIdx.x;
    const float* __restrict__ eb = em_g + (size_t)b * 2 * NLAB;

    // ---- stage emissions (C,L) -> LDS [l][c]; zero alpha ----
    // float4 LDS writes: lane stride 16 B -> 8 lanes/bank == b128's natural
    // 8-clock issue -> conflict-free.
    for (int l2 = tid; l2 < NLAB / 2; l2 += 256) {
        float2 e0 = reinterpret_cast<const float2*>(eb)[l2];
        float2 e1 = reinterpret_cast<const float2*>(eb + NLAB)[l2];
        reinterpret_cast<float4*>(em)[l2] = make_float4(e0.x, e1.x, e0.y, e1.y);
        reinterpret_cast<float4*>(al)[l2] = make_float4(0.f, 0.f, 0.f, 0.f);
    }
    __syncthreads();

    // ---- upward pass (deep -> shallow), child-per-lane ----
    // idx space i = child-1; parent p = i>>2; all starts are multiples of 4
    // and 256-chunks preserve 4-lane groups. idx 2047 (child 2048) is a
    // phantom: masked to msg=0.
    const int ustart[6] = {1364, 340, 84, 20, 4, 0};
    const int uend[6]   = {2048, 1364, 340, 84, 20, 4};
#pragma unroll
    for (int pass = 0; pass < 6; ++pass) {
        for (int i = ustart[pass] + tid; i < uend[pass]; i += 256) {
            const bool valid = (i + 1) < NLAB;
            const int c = valid ? i + 1 : NLAB - 1;     // clamp loads
            float2 e = reinterpret_cast<const float2*>(em)[c];
            float2 a = reinterpret_cast<const float2*>(al)[c];
            float l0 = e.x + a.x;            // local[yc=0]
            float l1 = e.y + a.y;            // local[yc=1]
            float4 t;                         // pairs[p][c][yp][yc]
            if (COMPACT) t = up[min(i, NLAB - 2)];
            else         t = pairs4[(size_t)(i >> 2) * NLAB + c];
            float m0 = valid ? lse2(t.x + l0, t.y + l1) : 0.f;  // msg[yp=0]
            float m1 = valid ? lse2(t.z + l0, t.w + l1) : 0.f;  // msg[yp=1]
            // sum the 4 children of one parent across the 4-lane group
            m0 += __shfl_xor(m0, 1, 4);  m0 += __shfl_xor(m0, 2, 4);
            m1 += __shfl_xor(m1, 1, 4);  m1 += __shfl_xor(m1, 2, 4);
            if ((i & 3) == 0)
                reinterpret_cast<float2*>(al)[i >> 2] = make_float2(m0, m1);
        }
        __syncthreads();
    }

    float* __restrict__ ob0 = out + (size_t)b * 2 * NLAB;
    float* __restrict__ ob1 = ob0 + NLAB;

    // ---- root: beta = 0 -> em[0..1] already pb; emit root output ----
    if (tid == 0) {
        float s0 = em[0] + al[0];
        float s1 = em[1] + al[1];
        float Z = lse2(s0, s1);
        ob0[0] = s0 - Z;
        ob1[0] = s1 - Z;
    }
    __syncthreads();

    // ---- downward pass (shallow -> deep), node-per-lane, fused output ----
    const int dstart[6] = {1, 5, 21, 85, 341, 1365};
    const int dend[6]   = {5, 21, 85, 341, 1365, 2048};
#pragma unroll
    for (int pass = 0; pass < 6; ++pass) {
        for (int n = dstart[pass] + tid; n < dend[pass]; n += 256) {
            const int par = (n - 1) >> 2;
            float2 pp = reinterpret_cast<const float2*>(em)[par];  // pb[par]
            float4 t;                         // pairs[n][par][yc][yp]
            if (COMPACT) t = down[n - 1];
            else         t = pairs4[(size_t)n * NLAB + par];
            float m0 = lse2(t.x + pp.x, t.y + pp.y);   // msg[yc=0]
            float m1 = lse2(t.z + pp.x, t.w + pp.y);   // msg[yc=1]
            float pb0 = em[n * 2 + 0] + m0;
            float pb1 = em[n * 2 + 1] + m1;
            em[n * 2 + 0] = pb0;   // in place: pb for this node's children
            em[n * 2 + 1] = pb1;
            float s0 = pb0 + al[n * 2 + 0];
            float s1 = pb1 + al[n * 2 + 1];
            float Z = lse2(s0, s1);
            ob0[n] = s0 - Z;
            ob1[n] = s1 - Z;
        }
        __syncthreads();
    }
}

extern "C" void kernel_launch(void* const* d_in, const int* in_sizes, int n_in,
                              void* d_out, int out_size, void* d_ws, size_t ws_size,
                              hipStream_t stream) {
    const float*  emissions = (const float*)d_in[0];
    const float4* pairs4    = (const float4*)d_in[1];
    float* outp             = (float*)d_out;

    const size_t need = 2 * (size_t)(NLAB - 1) * sizeof(float4);  // 65,504 B
    if (ws_size >= need) {
        float4* upw  = (float4*)d_ws;
        float4* dnw  = upw + (NLAB - 1);
        compact_pairs<<<dim3((NLAB + 255) / 256), dim3(256), 0, stream>>>(pairs4, upw, dnw);
        treecrf_kernel<true><<<dim3(NBATCH), dim3(256), 0, stream>>>(
            emissions, pairs4, upw, dnw, outp);
    } else {
        treecrf_kernel<false><<<dim3(NBATCH), dim3(256), 0, stream>>>(
            emissions, pairs4, nullptr, nullptr, outp);
    }
}

// Round 3
// 133.868 us; speedup vs baseline: 1.4017x; 1.4017x over previous
//
#include <hip/hip_runtime.h>

// TreeCRF belief propagation, B=2048, C=2, L=2048, BRANCH=4.
// One block per batch element; BP state in LDS (32 KB). Static tree:
// parent(i) = (i-1)>>2. Level starts {0,1,5,21,85,341,1365}; leaves 512..2047.
//
// Round-2 profile: VALU-bound (VALUBusy 65%, HBM 6.8%), log1pf libm polynomial
// dominated. This round: hardware v_exp_f32/v_log_f32 only, and per-edge
// precomputed exp-factors so each 2-class message pair costs 1 exp + 2 log.
// Exactness: msg = A + l0 + ln2*log2(1 + 2^((l1-l0)*log2e)*E) is the exact
// logsumexp; exponents are structurally bounded (class diffs ~<20 << 126).

constexpr int NLAB = 2048;
constexpr int NBATCH = 2048;

#define LOG2E 1.4426950408889634f
#define LN2   0.6931471805599453f

__device__ __forceinline__ float fexp2(float x) { return __builtin_amdgcn_exp2f(x); }
__device__ __forceinline__ float flog2(float x) { return __builtin_amdgcn_logf(x); }

// compacted edge record: {A0, A1, E0, E1}
//   A[yp] = t[yp][0],  E[yp] = 2^((t[yp][1]-t[yp][0])*log2e)
__global__ __launch_bounds__(256) void compact_pairs(
    const float4* __restrict__ pairs4,  // (L, L) of float4
    float4* __restrict__ up,            // edge child->parent: pairs[p][c], [yp][yc]
    float4* __restrict__ down)          // edge parent->child: pairs[c][p], [yc][yp]
{
    int i = blockIdx.x * 256 + threadIdx.x;
    if (i < NLAB - 1) {
        int c = i + 1, p = i >> 2;
        float4 t = pairs4[(size_t)p * NLAB + c];   // [yp][yc]
        up[i] = make_float4(t.x, t.z,
                            fexp2((t.y - t.x) * LOG2E),
                            fexp2((t.w - t.z) * LOG2E));
        float4 s = pairs4[(size_t)c * NLAB + p];   // [yc][yp]
        down[i] = make_float4(s.x, s.z,
                              fexp2((s.y - s.x) * LOG2E),
                              fexp2((s.w - s.z) * LOG2E));
    }
}

__global__ __launch_bounds__(256) void treecrf_kernel(
    const float* __restrict__ em_g,     // (B, 2, L)
    const float4* __restrict__ up,
    const float4* __restrict__ down,
    float* __restrict__ out)            // (B, 2, L)
{
    // em: interleaved [l*2+c]; overwritten in the downward pass with
    // pb[l][c] = emissions + beta (children need em[par]+beta[par]; final
    // score = alpha + pb).
    __shared__ float em[2 * NLAB];
    __shared__ float al[2 * NLAB];   // alpha accumulator, interleaved

    const int b = blockIdx.x;
    const int tid = threadIdx.x;
    const float* __restrict__ eb = em_g + (size_t)b * 2 * NLAB;

    // ---- stage emissions (C,L) -> LDS [l][c] (float4 writes, conflict-free);
    //      zero alpha ----
    for (int l2 = tid; l2 < NLAB / 2; l2 += 256) {
        float2 e0 = reinterpret_cast<const float2*>(eb)[l2];
        float2 e1 = reinterpret_cast<const float2*>(eb + NLAB)[l2];
        reinterpret_cast<float4*>(em)[l2] = make_float4(e0.x, e1.x, e0.y, e1.y);
        reinterpret_cast<float4*>(al)[l2] = make_float4(0.f, 0.f, 0.f, 0.f);
    }
    __syncthreads();

    // ---- upward pass (deep -> shallow), child-per-lane ----
    // i = child-1; parent = i>>2; starts are multiples of 4 so 4-lane groups
    // align with sibling groups. i=2047 (child 2048) is a phantom -> msg 0.
    const int ustart[6] = {1364, 340, 84, 20, 4, 0};
    const int uend[6]   = {2048, 1364, 340, 84, 20, 4};
#pragma unroll
    for (int pass = 0; pass < 6; ++pass) {
        for (int i = ustart[pass] + tid; i < uend[pass]; i += 256) {
            const bool valid = (i + 1) < NLAB;
            const int c = valid ? i + 1 : NLAB - 1;     // clamp loads
            float2 e = reinterpret_cast<const float2*>(em)[c];
            float l0 = e.x, l1 = e.y;
            if (pass > 0) {   // pass 0 children are all leaves: alpha == 0
                float2 a = reinterpret_cast<const float2*>(al)[c];
                l0 += a.x; l1 += a.y;
            }
            float4 t = up[min(i, NLAB - 2)];   // {A0, A1, E0, E1}
            float eu = fexp2((l1 - l0) * LOG2E);
            float m0 = t.x + l0 + LN2 * flog2(fmaf(eu, t.z, 1.f));
            float m1 = t.y + l0 + LN2 * flog2(fmaf(eu, t.w, 1.f));
            if (!valid) { m0 = 0.f; m1 = 0.f; }
            // sum the 4 siblings across the 4-lane group
            m0 += __shfl_xor(m0, 1, 4);  m0 += __shfl_xor(m0, 2, 4);
            m1 += __shfl_xor(m1, 1, 4);  m1 += __shfl_xor(m1, 2, 4);
            if ((i & 3) == 0)
                reinterpret_cast<float2*>(al)[i >> 2] = make_float2(m0, m1);
        }
        __syncthreads();
    }

    float* __restrict__ ob0 = out + (size_t)b * 2 * NLAB;
    float* __restrict__ ob1 = ob0 + NLAB;

    // ---- root: beta = 0 -> em[0..1] already pb; emit root output ----
    if (tid == 0) {
        float s0 = em[0] + al[0];
        float s1 = em[1] + al[1];
        float Z = s0 + LN2 * flog2(1.f + fexp2((s1 - s0) * LOG2E));
        ob0[0] = s0 - Z;
        ob1[0] = s1 - Z;
    }
    __syncthreads();

    // ---- downward pass (shallow -> deep), node-per-lane, fused output ----
    const int dstart[6] = {1, 5, 21, 85, 341, 1365};
    const int dend[6]   = {5, 21, 85, 341, 1365, 2048};
#pragma unroll
    for (int pass = 0; pass < 6; ++pass) {
        for (int n = dstart[pass] + tid; n < dend[pass]; n += 256) {
            const int par = (n - 1) >> 2;
            float2 pp = reinterpret_cast<const float2*>(em)[par];  // pb[par]
            float4 t = down[n - 1];   // {D0, D1, F0, F1}
            float eu = fexp2((pp.y - pp.x) * LOG2E);
            float m0 = t.x + pp.x + LN2 * flog2(fmaf(eu, t.z, 1.f));
            float m1 = t.y + pp.x + LN2 * flog2(fmaf(eu, t.w, 1.f));
            float pb0 = em[n * 2 + 0] + m0;
            float pb1 = em[n * 2 + 1] + m1;
            em[n * 2 + 0] = pb0;   // in place: pb for this node's children
            em[n * 2 + 1] = pb1;
            float s0 = pb0 + al[n * 2 + 0];
            float s1 = pb1 + al[n * 2 + 1];
            float Z = s0 + LN2 * flog2(1.f + fexp2((s1 - s0) * LOG2E));
            ob0[n] = s0 - Z;
            ob1[n] = s1 - Z;
        }
        __syncthreads();
    }
}

extern "C" void kernel_launch(void* const* d_in, const int* in_sizes, int n_in,
                              void* d_out, int out_size, void* d_ws, size_t ws_size,
                              hipStream_t stream) {
    const float*  emissions = (const float*)d_in[0];
    const float4* pairs4    = (const float4*)d_in[1];
    float* outp             = (float*)d_out;

    float4* upw = (float4*)d_ws;
    float4* dnw = upw + (NLAB - 1);
    compact_pairs<<<dim3((NLAB + 255) / 256), dim3(256), 0, stream>>>(pairs4, upw, dnw);
    treecrf_kernel<<<dim3(NBATCH), dim3(256), 0, stream>>>(emissions, upw, dnw, outp);
}